// Round 17
// baseline (508.315 us; speedup 1.0000x reference)
//
#include <hip/hip_runtime.h>
#include <cstddef>

#pragma clang fp contract(off)

#define B_    32
#define N_    16384
#define NPTS  (B_ * N_)              // 524288
#define FEATSZ (32 * 67 * 64 * 16)   // 2195456
#define NCHUNK (NPTS / 64)           // 8192 chunks
#define GRID_Y2 1024                 // 8 chunks/block, tree amortized
#define GRID_XS 512

// ---- workspace layout ----
// f64 offsets (double*)
enum : int {
  D_X9    = 0,     // 9   (written by k_redX)
  D_Y3SUM = 16,    // 64  (atomic -> zeroed)
  D_Y3SQ  = 80,    // 64  (atomic -> zeroed)  [zero first 144 doubles]
  D_XPART = 1024,  // 512*9 partials
};
// f32 offsets (float*), region starts at byte 65536
enum : int {
  F_M1   = 16384,  // 64
  F_R1   = 16448,  // 64
  F_M2   = 16512,  // 128
  F_R2   = 16640,  // 128
  F_M3   = 16768,  // 64
  F_R3   = 16832,  // 64
  F_W2T  = 16896,  // 8192 transposed w2 [c][o]
  F_W3T  = 25088,  // 8192 transposed w3 [o][q]
  F_TOPK = 33280,  // 2048*16 int32
};
#define Y3_B     524288
#define Y2PART_B 524288   // partials overlay y3 (disjoint lifetime)

// Faithful f32 layer-1 forward: identical expression everywhere -> bit-identical h1.
__device__ __forceinline__ float h1_of(const float* __restrict__ w1,
                                       const float* __restrict__ b1,
                                       const float* __restrict__ g1,
                                       const float* __restrict__ be1,
                                       const float* __restrict__ fw, int c,
                                       float x0, float x1, float x2) {
  float s = w1[c*3+0] * x0;
  s = fmaf(w1[c*3+1], x1, s);
  s = fmaf(w1[c*3+2], x2, s);
  float y1 = s + b1[c];
  float t = y1 - fw[F_M1 + c];
  float u = t * fw[F_R1 + c];
  u = u * g1[c];
  u = u + be1[c];
  return fmaxf(u, 0.f);
}

__device__ __forceinline__ unsigned int okey(float f) {
  unsigned int u = __float_as_uint(f);
  return (u & 0x80000000u) ? ~u : (u | 0x80000000u);
}

// ---- K1: f64 mean + 3x3 second moment of x; per-block partials (no atomics) ----
__global__ __launch_bounds__(256) void k_xstats64(const float* __restrict__ x,
                                                  double* __restrict__ wd) {
  __shared__ double sacc[4][9];
  double a0=0,a1=0,a2=0,m00=0,m01=0,m02=0,m11=0,m12=0,m22=0;
  for (int p = blockIdx.x * 256 + threadIdx.x; p < NPTS; p += gridDim.x * 256) {
    int b = p >> 14, n = p & (N_ - 1);
    const float* xb = x + (size_t)b * 3 * N_ + n;
    double x0 = xb[0], x1 = xb[N_], x2 = xb[2 * N_];
    a0 += x0; a1 += x1; a2 += x2;
    m00 = fma(x0,x0,m00); m01 = fma(x0,x1,m01); m02 = fma(x0,x2,m02);
    m11 = fma(x1,x1,m11); m12 = fma(x1,x2,m12); m22 = fma(x2,x2,m22);
  }
  #pragma unroll
  for (int m = 32; m >= 1; m >>= 1) {
    a0 += __shfl_xor(a0, m); a1 += __shfl_xor(a1, m); a2 += __shfl_xor(a2, m);
    m00 += __shfl_xor(m00, m); m01 += __shfl_xor(m01, m); m02 += __shfl_xor(m02, m);
    m11 += __shfl_xor(m11, m); m12 += __shfl_xor(m12, m); m22 += __shfl_xor(m22, m);
  }
  const int wv = threadIdx.x >> 6;
  if ((threadIdx.x & 63) == 0) {
    sacc[wv][0] = a0;  sacc[wv][1] = a1;  sacc[wv][2] = a2;
    sacc[wv][3] = m00; sacc[wv][4] = m01; sacc[wv][5] = m02;
    sacc[wv][6] = m11; sacc[wv][7] = m12; sacc[wv][8] = m22;
  }
  __syncthreads();
  if (threadIdx.x < 9) {
    double s = ((sacc[0][threadIdx.x] + sacc[1][threadIdx.x])
              + sacc[2][threadIdx.x]) + sacc[3][threadIdx.x];
    wd[D_XPART + blockIdx.x * 9 + threadIdx.x] = s;
  }
}

// ---- K1b: fixed-order reduction of x-stat partials ----
__global__ __launch_bounds__(64) void k_redX(double* __restrict__ wd) {
  int j = threadIdx.x;
  if (j >= 9) return;
  double s = 0.0;
  for (int b = 0; b < GRID_XS; ++b) s += wd[D_XPART + b * 9 + j];
  wd[D_X9 + j] = s;
}

// ---------------- K2: BN1 f32 coefficients from exact x-moments ----------------
__global__ void k_prep1(const float* __restrict__ w1, const float* __restrict__ b1,
                        double* __restrict__ wd, float* __restrict__ fw) {
  int c = threadIdx.x;
  if (c >= 64) return;
  const double inv = 1.0 / (double)NPTS;
  double mx0 = wd[0]*inv, mx1 = wd[1]*inv, mx2 = wd[2]*inv;
  double c00 = wd[3]*inv - mx0*mx0, c01 = wd[4]*inv - mx0*mx1, c02 = wd[5]*inv - mx0*mx2;
  double c11 = wd[6]*inv - mx1*mx1, c12 = wd[7]*inv - mx1*mx2, c22 = wd[8]*inv - mx2*mx2;
  double w0 = w1[c*3+0], w1_ = w1[c*3+1], w2_ = w1[c*3+2];
  double m1 = w0*mx0 + w1_*mx1 + w2_*mx2 + (double)b1[c];
  double var = w0*w0*c00 + w1_*w1_*c11 + w2_*w2_*c22
             + 2.0*(w0*w1_*c01 + w0*w2_*c02 + w1_*w2_*c12);
  fw[F_M1 + c] = (float)m1;
  float vpe = (float)var + 1e-5f;
  fw[F_R1 + c] = (float)(1.0 / sqrt((double)vpe));
}

// ---------------- K2b: weight transposes (no stat dependency) ----------------
__global__ __launch_bounds__(64) void k_prepW(const float* __restrict__ w2,
                                              const float* __restrict__ w3,
                                              float* __restrict__ fw) {
  const int o = blockIdx.x, c = threadIdx.x;   // o 0..127, c 0..63
  fw[F_W2T + c * 128 + o] = w2[o * 64 + c];    // [c][o]
  fw[F_W3T + o * 64 + c] = w3[c * 128 + o];    // [o][q]
}

// ------- K3: y2 f64 moments; 16 waves/block, o-chunk 8, x-PREFETCHED (T14) -------
// Load reordering only: next chunk's x issued during phase-B FMAs; all value
// chains and f64 accumulation order identical to R16 -> bit-identical results.
__global__ __launch_bounds__(1024, 8) void k_y2stats(const float* __restrict__ x,
                                                     const float* __restrict__ w1,
                                                     const float* __restrict__ b1,
                                                     const float* __restrict__ g1,
                                                     const float* __restrict__ be1,
                                                     const float* __restrict__ fw,
                                                     double* __restrict__ y2part) {
  __shared__ float h1g[16][64][4];   // [c-granule][point][elem] 16 KB
  const int tid = threadIdx.x;
  const int lane = tid & 63;
  const int wvu = __builtin_amdgcn_readfirstlane(tid >> 6);  // 0..15
  const int o0 = wvu * 8;
  const float* w2t = fw + F_W2T;
  double s64[8], q64[8];
  #pragma unroll
  for (int j = 0; j < 8; ++j) { s64[j] = 0.0; q64[j] = 0.0; }

  float px0, px1, px2;
  {
    int p = blockIdx.x * 64 + lane;
    int b = p >> 14, n = p & (N_ - 1);
    const float* xb = x + (size_t)b * 3 * N_ + n;
    px0 = xb[0]; px1 = xb[N_]; px2 = xb[2 * N_];
  }

  for (int chunk = blockIdx.x; chunk < NCHUNK; chunk += GRID_Y2) {
    __syncthreads();   // prior-iteration readers done before overwrite
    {
      const int c0 = wvu * 4;
      float hv[4];
      #pragma unroll
      for (int k = 0; k < 4; ++k) hv[k] = h1_of(w1, b1, g1, be1, fw, c0 + k, px0, px1, px2);
      float4 v; v.x = hv[0]; v.y = hv[1]; v.z = hv[2]; v.w = hv[3];
      *(float4*)&h1g[wvu][lane][0] = v;
    }
    __syncthreads();
    // prefetch next chunk's x (latency hides under the FMA loop)
    float nx0 = 0.f, nx1 = 0.f, nx2 = 0.f;
    {
      int nchunk = chunk + GRID_Y2;
      if (nchunk < NCHUNK) {
        int p = nchunk * 64 + lane;
        int b = p >> 14, n = p & (N_ - 1);
        const float* xb = x + (size_t)b * 3 * N_ + n;
        nx0 = xb[0]; nx1 = xb[N_]; nx2 = xb[2 * N_];
      }
    }
    float acc[8];
    #pragma unroll
    for (int j = 0; j < 8; ++j) acc[j] = 0.f;
    #pragma unroll 4
    for (int cg = 0; cg < 16; ++cg) {
      float4 hgv = *(const float4*)&h1g[cg][lane][0];
      float hx[4] = {hgv.x, hgv.y, hgv.z, hgv.w};
      #pragma unroll
      for (int e = 0; e < 4; ++e) {
        const int c = cg * 4 + e;
        const float hc = hx[e];
        const float* wc = w2t + c * 128 + o0;
        #pragma unroll
        for (int j = 0; j < 8; ++j) acc[j] = fmaf(wc[j], hc, acc[j]);
      }
    }
    #pragma unroll
    for (int j = 0; j < 8; ++j) {
      double v = (double)acc[j];
      s64[j] += v;
      q64[j] = fma(v, v, q64[j]);
    }
    px0 = nx0; px1 = nx1; px2 = nx2;
  }
  #pragma unroll
  for (int j = 0; j < 8; ++j) {
    #pragma unroll
    for (int m = 32; m >= 1; m >>= 1) {
      s64[j] += __shfl_xor(s64[j], m);
      q64[j] += __shfl_xor(q64[j], m);
    }
  }
  if (lane == 0) {
    #pragma unroll
    for (int j = 0; j < 8; ++j) {
      int o = o0 + j;
      y2part[((size_t)blockIdx.x * 128 + o) * 2 + 0] = s64[j];
      y2part[((size_t)blockIdx.x * 128 + o) * 2 + 1] = q64[j];
    }
  }
}

// ---- K3b: fixed-order partial reduction (1024 partials) + BN2 coeffs, fused ----
// Same f64 expression sequence as the former redY2+prep2s (value passed in
// register instead of via memory) -> identical arithmetic.
__global__ __launch_bounds__(256) void k_redY2p(const double* __restrict__ y2part,
                                                const float* __restrict__ b2,
                                                float* __restrict__ fw) {
  __shared__ double ss[256], sq[256];
  const int o = blockIdx.x, tid = threadIdx.x;
  double s = 0.0, q = 0.0;
  for (int blk = tid; blk < GRID_Y2; blk += 256) {
    s += y2part[((size_t)blk * 128 + o) * 2 + 0];
    q += y2part[((size_t)blk * 128 + o) * 2 + 1];
  }
  ss[tid] = s; sq[tid] = q;
  __syncthreads();
  for (int st = 128; st > 0; st >>= 1) {
    if (tid < st) { ss[tid] += ss[tid + st]; sq[tid] += sq[tid + st]; }
    __syncthreads();
  }
  if (tid == 0) {
    const double inv = 1.0 / (double)NPTS;
    double mraw = ss[0] * inv;
    double var = sq[0] * inv - mraw * mraw;
    fw[F_M2 + o] = (float)(mraw + (double)b2[o]);
    float vpe = (float)var + 1e-5f;
    fw[F_R2 + o] = (float)(1.0 / sqrt((double)vpe));
  }
}

// -------- K5: forward, 2 chunks/block with x-prefetch (math verbatim R16) --------
__global__ __launch_bounds__(512, 4) void k_fwd(const float* __restrict__ x,
                                                const float* __restrict__ w1,
                                                const float* __restrict__ b1,
                                                const float* __restrict__ g1,
                                                const float* __restrict__ be1,
                                                const float* __restrict__ b2,
                                                const float* __restrict__ g2,
                                                const float* __restrict__ be2,
                                                const float* __restrict__ b3,
                                                const float* __restrict__ fw,
                                                float* __restrict__ y3out) {
  __shared__ float h1g[16][64][4];   // 16 KB
  __shared__ float h2g[16][64][4];   // 16 KB
  const int tid = threadIdx.x;
  const int lane = tid & 63;
  const int wvu = __builtin_amdgcn_readfirstlane(tid >> 6);  // 0..7
  const float* w2t = fw + F_W2T;
  const float* w3t = fw + F_W3T;
  const int q0 = wvu * 8;

  float px0, px1, px2;
  {
    int p = blockIdx.x * 128 + lane;
    int b = p >> 14, n = p & (N_ - 1);
    const float* xb = x + (size_t)b * 3 * N_ + n;
    px0 = xb[0]; px1 = xb[N_]; px2 = xb[2 * N_];
  }

  #pragma unroll 1
  for (int it = 0; it < 2; ++it) {
    const int p = blockIdx.x * 128 + it * 64 + lane;
    const int b = p >> 14, n = p & (N_ - 1);
    float a3[8];

    // phase A: h1 from the prefetched x
    {
      const int c0 = wvu * 8;
      float hv[8];
      #pragma unroll
      for (int k = 0; k < 8; ++k) hv[k] = h1_of(w1, b1, g1, be1, fw, c0 + k, px0, px1, px2);
      #pragma unroll
      for (int gq = 0; gq < 2; ++gq) {
        float4 v; v.x = hv[gq*4+0]; v.y = hv[gq*4+1]; v.z = hv[gq*4+2]; v.w = hv[gq*4+3];
        *(float4*)&h1g[(c0 >> 2) + gq][lane][0] = v;
      }
    }
    __syncthreads();

    // prefetch second chunk's x during first chunk's compute
    if (it == 0) {
      int p2 = blockIdx.x * 128 + 64 + lane;
      int b2_ = p2 >> 14, n2 = p2 & (N_ - 1);
      const float* xb = x + (size_t)b2_ * 3 * N_ + n2;
      px0 = xb[0]; px1 = xb[N_]; px2 = xb[2 * N_];
    }

    #pragma unroll
    for (int H = 0; H < 2; ++H) {
      {
        const int o0 = H * 64 + wvu * 8;
        float acc[8];
        #pragma unroll
        for (int j = 0; j < 8; ++j) acc[j] = 0.f;
        #pragma unroll 4
        for (int cg = 0; cg < 16; ++cg) {
          float4 hgv = *(const float4*)&h1g[cg][lane][0];
          float hx[4] = {hgv.x, hgv.y, hgv.z, hgv.w};
          #pragma unroll
          for (int e = 0; e < 4; ++e) {
            const int c = cg * 4 + e;
            const float hc = hx[e];
            const float* wc = w2t + c * 128 + o0;
            #pragma unroll
            for (int j = 0; j < 8; ++j) acc[j] = fmaf(wc[j], hc, acc[j]);
          }
        }
        float hv2[8];
        #pragma unroll
        for (int j = 0; j < 8; ++j) {
          int o = o0 + j;
          float y2 = acc[j] + b2[o];
          float t = y2 - fw[F_M2 + o];
          float u = t * fw[F_R2 + o];
          u = u * g2[o];
          u = u + be2[o];
          hv2[j] = fmaxf(u, 0.f);
        }
        #pragma unroll
        for (int gq = 0; gq < 2; ++gq) {
          float4 v; v.x = hv2[gq*4+0]; v.y = hv2[gq*4+1]; v.z = hv2[gq*4+2]; v.w = hv2[gq*4+3];
          *(float4*)&h2g[wvu * 2 + gq][lane][0] = v;
        }
      }
      __syncthreads();
      {
        #pragma unroll 4
        for (int og = 0; og < 16; ++og) {
          float4 hgv = *(const float4*)&h2g[og][lane][0];
          float hx[4] = {hgv.x, hgv.y, hgv.z, hgv.w};
          #pragma unroll
          for (int e = 0; e < 4; ++e) {
            const int o = H * 64 + og * 4 + e;
            const float ho = hx[e];
            const float* wr = w3t + o * 64 + q0;
            if (H == 0 && og == 0 && e == 0) {
              #pragma unroll
              for (int j = 0; j < 8; ++j) a3[j] = wr[j] * ho;
            } else {
              #pragma unroll
              for (int j = 0; j < 8; ++j) a3[j] = fmaf(wr[j], ho, a3[j]);
            }
          }
        }
      }
      __syncthreads();
    }

    float* yrow = y3out + (size_t)b * 64 * N_ + n;
    #pragma unroll
    for (int j = 0; j < 8; ++j) {
      int q = q0 + j;
      yrow[(size_t)q * N_] = a3[j] + b3[q];
    }
  }
}

__global__ void k_prep3(double* __restrict__ wd, float* __restrict__ fw) {
  int o = threadIdx.x;
  if (o >= 64) return;
  const double inv = 1.0 / (double)NPTS;
  double m = wd[D_Y3SUM + o] * inv;
  double var = wd[D_Y3SQ + o] * inv - m * m;
  fw[F_M3 + o] = (float)m;
  float vpe = (float)var + 1e-5f;
  fw[F_R3 + o] = (float)(1.0 / sqrt((double)vpe));
}

// -------- K6: radix-select top-16 of sgn(g3)*y3 per (b,c) row + fused y3 stats --------
__global__ __launch_bounds__(256) void k_topk(const float* __restrict__ y3,
                                              const float* __restrict__ g3,
                                              int* __restrict__ topk,
                                              double* __restrict__ wd) {
  __shared__ unsigned int hist[4][256];
  __shared__ unsigned int cnt[256];
  __shared__ unsigned long long buf[256];
  __shared__ unsigned int nbuf;
  __shared__ int s_tbin1, s_before1, s_tbin2;
  __shared__ double ssum[256], ssq[256];
  const int tid = threadIdx.x;
  const int row = blockIdx.x;
  const int c = row & 63;
  const int wv = tid >> 6;
  const float sgn = (g3[c] >= 0.f) ? 1.f : -1.f;
  const float4* y = (const float4*)(y3 + (size_t)row * N_);

  for (int i = tid; i < 1024; i += 256) ((unsigned int*)hist)[i] = 0;
  if (tid == 0) nbuf = 0;
  __syncthreads();

  // scan 1: stats (verbatim order) + top-byte histogram
  double s = 0.0, q = 0.0;
  #pragma unroll 1
  for (int it = 0; it < 16; ++it) {
    int n4 = it * 256 + tid;
    float4 v = y[n4];
    {
      double a = v.x, bb = v.y, cc2 = v.z, d = v.w;
      s += a + bb + cc2 + d;
      q = fma(a,a,q); q = fma(bb,bb,q); q = fma(cc2,cc2,q); q = fma(d,d,q);
    }
    unsigned int u0 = okey(sgn * v.x), u1 = okey(sgn * v.y);
    unsigned int u2 = okey(sgn * v.z), u3 = okey(sgn * v.w);
    atomicAdd(&hist[wv][u0 >> 24], 1u);
    atomicAdd(&hist[wv][u1 >> 24], 1u);
    atomicAdd(&hist[wv][u2 >> 24], 1u);
    atomicAdd(&hist[wv][u3 >> 24], 1u);
  }
  ssum[tid] = s; ssq[tid] = q;
  __syncthreads();
  for (int st = 128; st > 0; st >>= 1) {
    if (tid < st) { ssum[tid] += ssum[tid + st]; ssq[tid] += ssq[tid + st]; }
    __syncthreads();
  }
  if (tid == 0) {
    atomicAdd(&wd[D_Y3SUM + c], ssum[0]);
    atomicAdd(&wd[D_Y3SQ  + c], ssq[0]);
  }

  unsigned int myc = hist[0][tid] + hist[1][tid] + hist[2][tid] + hist[3][tid];
  cnt[tid] = myc;
  __syncthreads();
  for (int st = 1; st < 256; st <<= 1) {
    unsigned int t = (tid >= st) ? cnt[tid - st] : 0u;
    __syncthreads();
    cnt[tid] += t;
    __syncthreads();
  }
  {
    unsigned int incl = cnt[tid], excl = incl - myc;
    if (excl < 16u && incl >= 16u) { s_tbin1 = tid; s_before1 = (int)excl; }
  }
  __syncthreads();
  const unsigned int tbin1 = (unsigned int)s_tbin1;
  const int before1 = s_before1;

  for (int i = tid; i < 1024; i += 256) ((unsigned int*)hist)[i] = 0;
  __syncthreads();
  #pragma unroll 1
  for (int it = 0; it < 16; ++it) {
    int n4 = it * 256 + tid;
    float4 v = y[n4];
    unsigned int u0 = okey(sgn * v.x), u1 = okey(sgn * v.y);
    unsigned int u2 = okey(sgn * v.z), u3 = okey(sgn * v.w);
    if ((u0 >> 24) == tbin1) atomicAdd(&hist[wv][(u0 >> 16) & 255u], 1u);
    if ((u1 >> 24) == tbin1) atomicAdd(&hist[wv][(u1 >> 16) & 255u], 1u);
    if ((u2 >> 24) == tbin1) atomicAdd(&hist[wv][(u2 >> 16) & 255u], 1u);
    if ((u3 >> 24) == tbin1) atomicAdd(&hist[wv][(u3 >> 16) & 255u], 1u);
  }
  __syncthreads();
  myc = hist[0][tid] + hist[1][tid] + hist[2][tid] + hist[3][tid];
  cnt[tid] = myc;
  __syncthreads();
  for (int st = 1; st < 256; st <<= 1) {
    unsigned int t = (tid >= st) ? cnt[tid - st] : 0u;
    __syncthreads();
    cnt[tid] += t;
    __syncthreads();
  }
  {
    const unsigned int r2 = (unsigned int)(16 - before1);
    unsigned int incl = cnt[tid], excl = incl - myc;
    if (excl < r2 && incl >= r2) s_tbin2 = tid;
  }
  __syncthreads();
  const unsigned int thresh16 = (tbin1 << 8) | (unsigned int)s_tbin2;

  #pragma unroll 1
  for (int it = 0; it < 16; ++it) {
    int n4 = it * 256 + tid;
    float4 v = y[n4];
    int nb = n4 * 4;
    unsigned int uu[4] = { okey(sgn * v.x), okey(sgn * v.y),
                           okey(sgn * v.z), okey(sgn * v.w) };
    #pragma unroll
    for (int j = 0; j < 4; ++j) {
      if ((uu[j] >> 16) <= thresh16) {
        unsigned int slot = atomicAdd(&nbuf, 1u);
        if (slot < 256u)
          buf[slot] = ((unsigned long long)uu[j] << 32) | (unsigned int)(nb + j);
      }
    }
  }
  __syncthreads();

  if (tid < 64) {
    const unsigned int m = nbuf < 256u ? nbuf : 256u;
    const unsigned long long MAXK = ~0ull;
    unsigned long long k0 = (tid +   0u) < m ? buf[tid +   0] : MAXK;
    unsigned long long k1 = (tid +  64u) < m ? buf[tid +  64] : MAXK;
    unsigned long long k2 = (tid + 128u) < m ? buf[tid + 128] : MAXK;
    unsigned long long k3 = (tid + 192u) < m ? buf[tid + 192] : MAXK;
    #pragma unroll 1
    for (int r = 0; r < 16; ++r) {
      unsigned long long a = k0 < k1 ? k0 : k1;
      unsigned long long b = k2 < k3 ? k2 : k3;
      unsigned long long kmin = a < b ? a : b;
      #pragma unroll
      for (int m2 = 32; m2 >= 1; m2 >>= 1) {
        unsigned long long o = __shfl_xor(kmin, m2);
        kmin = o < kmin ? o : kmin;
      }
      bool have = (k0 == kmin) | (k1 == kmin) | (k2 == kmin) | (k3 == kmin);
      unsigned long long bal = __ballot(have);
      int wlane = __ffsll((unsigned long long)bal) - 1;
      if (tid == wlane) {
        if (k0 == kmin) k0 = MAXK;
        else if (k1 == kmin) k1 = MAXK;
        else if (k2 == kmin) k2 = MAXK;
        else k3 = MAXK;
      }
      if (tid == 0) topk[row * 16 + r] = (int)(kmin & 0xFFFFFFFFull);
    }
  }
}

// ---------------- K7: gather feat (faithful BN3 apply) + idx as float ----------------
__global__ __launch_bounds__(256) void k_gather(const float* __restrict__ x,
                                                const float* __restrict__ fw,
                                                const float* __restrict__ g3,
                                                const float* __restrict__ be3,
                                                const float* __restrict__ y3,
                                                const int* __restrict__ topk,
                                                float* __restrict__ out) {
  __shared__ int s_i[16];
  __shared__ float s_m[64], s_r[64], s_g[64], s_b[64];
  const int tid = threadIdx.x;
  const int row = blockIdx.x;
  const int b = row >> 6, c = row & 63;
  if (tid < 16) s_i[tid] = topk[row * 16 + tid];
  if (tid < 64) {
    s_m[tid] = fw[F_M3 + tid]; s_r[tid] = fw[F_R3 + tid];
    s_g[tid] = g3[tid];        s_b[tid] = be3[tid];
  }
  __syncthreads();
  for (int t = tid; t < 67 * 16; t += 256) {
    int ch = t >> 4, n = t & 15, i = s_i[n];
    float v;
    if (ch < 3) {
      v = x[((size_t)b * 3 + ch) * N_ + i];
    } else {
      int c2 = ch - 3;
      float yv = y3[((size_t)b * 64 + c2) * N_ + i];
      float tt = yv - s_m[c2];
      float u = tt * s_r[c2];
      u = u * s_g[c2];
      v = u + s_b[c2];
    }
    out[(((size_t)b * 67 + ch) * 64 + c) * 16 + n] = v;
  }
  if (tid < 48) {
    int ch = tid >> 4, n = tid & 15;
    out[FEATSZ + (((size_t)b * 3 + ch) * 64 + c) * 16 + n] = (float)s_i[n];
  }
}

extern "C" void kernel_launch(void* const* d_in, const int* in_sizes, int n_in,
                              void* d_out, int out_size, void* d_ws, size_t ws_size,
                              hipStream_t stream) {
  const float* x   = (const float*)d_in[0];
  const float* w1  = (const float*)d_in[1];
  const float* b1  = (const float*)d_in[2];
  const float* g1  = (const float*)d_in[3];
  const float* be1 = (const float*)d_in[4];
  const float* w2  = (const float*)d_in[5];
  const float* b2  = (const float*)d_in[6];
  const float* g2  = (const float*)d_in[7];
  const float* be2 = (const float*)d_in[8];
  const float* w3  = (const float*)d_in[9];
  const float* b3  = (const float*)d_in[10];
  const float* g3  = (const float*)d_in[11];
  const float* be3 = (const float*)d_in[12];
  double* wd = (double*)d_ws;
  float*  fw = (float*)d_ws;
  float*  out = (float*)d_out;
  int* topk = (int*)(fw + F_TOPK);
  double* y2part = (double*)((char*)d_ws + Y2PART_B);
  float*  y3     = (float*)((char*)d_ws + Y3_B);

  hipMemsetAsync(d_ws, 0, 1152, stream);   // zero D_X9..D_Y3SQ (Y3 stats atomics)
  k_xstats64<<<GRID_XS, 256, 0, stream>>>(x, wd);
  k_redX    <<<1, 64, 0, stream>>>(wd);
  k_prep1   <<<1, 64, 0, stream>>>(w1, b1, wd, fw);
  k_prepW   <<<128, 64, 0, stream>>>(w2, w3, fw);
  k_y2stats <<<GRID_Y2, 1024, 0, stream>>>(x, w1, b1, g1, be1, fw, y2part);
  k_redY2p  <<<128, 256, 0, stream>>>(y2part, b2, fw);
  k_fwd     <<<NPTS / 128, 512, 0, stream>>>(x, w1, b1, g1, be1, b2, g2, be2, b3, fw, y3);
  k_topk    <<<B_ * 64, 256, 0, stream>>>(y3, g3, topk, wd);
  k_prep3   <<<1, 64, 0, stream>>>(wd, fw);
  k_gather  <<<B_ * 64, 256, 0, stream>>>(x, fw, g3, be3, y3, topk, out);
  (void)in_sizes; (void)n_in; (void)out_size; (void)ws_size;
}

// Round 18
// 501.032 us; speedup vs baseline: 1.0145x; 1.0145x over previous
//
#include <hip/hip_runtime.h>
#include <cstddef>

#pragma clang fp contract(off)

#define B_    32
#define N_    16384
#define NPTS  (B_ * N_)              // 524288
#define FEATSZ (32 * 67 * 64 * 16)   // 2195456
#define NCHUNK (NPTS / 64)           // 8192 chunks
#define GRID_Y2 1024                 // 8 chunks/block, tree amortized
#define GRID_XS 512

// ---- workspace layout ----
// f64 offsets (double*)
enum : int {
  D_X9    = 0,     // 9   (written by k_redX)
  D_Y3SUM = 16,    // 64  (atomic -> zeroed)
  D_Y3SQ  = 80,    // 64  (atomic -> zeroed)  [zero first 144 doubles]
  D_XPART = 1024,  // 512*9 partials
};
// f32 offsets (float*), region starts at byte 65536
enum : int {
  F_M1   = 16384,  // 64
  F_R1   = 16448,  // 64
  F_M2   = 16512,  // 128
  F_R2   = 16640,  // 128
  F_M3   = 16768,  // 64
  F_R3   = 16832,  // 64
  F_W2T  = 16896,  // 8192 transposed w2 [c][o]
  F_W3T  = 25088,  // 8192 transposed w3 [o][q]
  F_TOPK = 33280,  // 2048*16 int32
};
#define Y3_B     524288
#define Y2PART_B 524288   // partials overlay y3 (disjoint lifetime)

// Faithful f32 layer-1 forward: identical expression everywhere -> bit-identical h1.
__device__ __forceinline__ float h1_of(const float* __restrict__ w1,
                                       const float* __restrict__ b1,
                                       const float* __restrict__ g1,
                                       const float* __restrict__ be1,
                                       const float* __restrict__ fw, int c,
                                       float x0, float x1, float x2) {
  float s = w1[c*3+0] * x0;
  s = fmaf(w1[c*3+1], x1, s);
  s = fmaf(w1[c*3+2], x2, s);
  float y1 = s + b1[c];
  float t = y1 - fw[F_M1 + c];
  float u = t * fw[F_R1 + c];
  u = u * g1[c];
  u = u + be1[c];
  return fmaxf(u, 0.f);
}

__device__ __forceinline__ unsigned int okey(float f) {
  unsigned int u = __float_as_uint(f);
  return (u & 0x80000000u) ? ~u : (u | 0x80000000u);
}

// ---- K1: f64 mean + 3x3 second moment of x; per-block partials (no atomics) ----
__global__ __launch_bounds__(256) void k_xstats64(const float* __restrict__ x,
                                                  double* __restrict__ wd) {
  __shared__ double sacc[4][9];
  double a0=0,a1=0,a2=0,m00=0,m01=0,m02=0,m11=0,m12=0,m22=0;
  for (int p = blockIdx.x * 256 + threadIdx.x; p < NPTS; p += gridDim.x * 256) {
    int b = p >> 14, n = p & (N_ - 1);
    const float* xb = x + (size_t)b * 3 * N_ + n;
    double x0 = xb[0], x1 = xb[N_], x2 = xb[2 * N_];
    a0 += x0; a1 += x1; a2 += x2;
    m00 = fma(x0,x0,m00); m01 = fma(x0,x1,m01); m02 = fma(x0,x2,m02);
    m11 = fma(x1,x1,m11); m12 = fma(x1,x2,m12); m22 = fma(x2,x2,m22);
  }
  #pragma unroll
  for (int m = 32; m >= 1; m >>= 1) {
    a0 += __shfl_xor(a0, m); a1 += __shfl_xor(a1, m); a2 += __shfl_xor(a2, m);
    m00 += __shfl_xor(m00, m); m01 += __shfl_xor(m01, m); m02 += __shfl_xor(m02, m);
    m11 += __shfl_xor(m11, m); m12 += __shfl_xor(m12, m); m22 += __shfl_xor(m22, m);
  }
  const int wv = threadIdx.x >> 6;
  if ((threadIdx.x & 63) == 0) {
    sacc[wv][0] = a0;  sacc[wv][1] = a1;  sacc[wv][2] = a2;
    sacc[wv][3] = m00; sacc[wv][4] = m01; sacc[wv][5] = m02;
    sacc[wv][6] = m11; sacc[wv][7] = m12; sacc[wv][8] = m22;
  }
  __syncthreads();
  if (threadIdx.x < 9) {
    double s = ((sacc[0][threadIdx.x] + sacc[1][threadIdx.x])
              + sacc[2][threadIdx.x]) + sacc[3][threadIdx.x];
    wd[D_XPART + blockIdx.x * 9 + threadIdx.x] = s;
  }
}

// ---- K1b: fixed-order reduction of x-stat partials ----
__global__ __launch_bounds__(64) void k_redX(double* __restrict__ wd) {
  int j = threadIdx.x;
  if (j >= 9) return;
  double s = 0.0;
  for (int b = 0; b < GRID_XS; ++b) s += wd[D_XPART + b * 9 + j];
  wd[D_X9 + j] = s;
}

// ---------------- K2: BN1 f32 coefficients from exact x-moments ----------------
__global__ void k_prep1(const float* __restrict__ w1, const float* __restrict__ b1,
                        double* __restrict__ wd, float* __restrict__ fw) {
  int c = threadIdx.x;
  if (c >= 64) return;
  const double inv = 1.0 / (double)NPTS;
  double mx0 = wd[0]*inv, mx1 = wd[1]*inv, mx2 = wd[2]*inv;
  double c00 = wd[3]*inv - mx0*mx0, c01 = wd[4]*inv - mx0*mx1, c02 = wd[5]*inv - mx0*mx2;
  double c11 = wd[6]*inv - mx1*mx1, c12 = wd[7]*inv - mx1*mx2, c22 = wd[8]*inv - mx2*mx2;
  double w0 = w1[c*3+0], w1_ = w1[c*3+1], w2_ = w1[c*3+2];
  double m1 = w0*mx0 + w1_*mx1 + w2_*mx2 + (double)b1[c];
  double var = w0*w0*c00 + w1_*w1_*c11 + w2_*w2_*c22
             + 2.0*(w0*w1_*c01 + w0*w2_*c02 + w1_*w2_*c12);
  fw[F_M1 + c] = (float)m1;
  float vpe = (float)var + 1e-5f;
  fw[F_R1 + c] = (float)(1.0 / sqrt((double)vpe));
}

// ---------------- K2b: weight transposes (no stat dependency) ----------------
__global__ __launch_bounds__(64) void k_prepW(const float* __restrict__ w2,
                                              const float* __restrict__ w3,
                                              float* __restrict__ fw) {
  const int o = blockIdx.x, c = threadIdx.x;   // o 0..127, c 0..63
  fw[F_W2T + c * 128 + o] = w2[o * 64 + c];    // [c][o]
  fw[F_W3T + o * 64 + c] = w3[c * 128 + o];    // [o][q]
}

// ------- K3: y2 f64 moments; 16 waves/block, o-chunk 8, x-prefetched (R17) -------
__global__ __launch_bounds__(1024, 8) void k_y2stats(const float* __restrict__ x,
                                                     const float* __restrict__ w1,
                                                     const float* __restrict__ b1,
                                                     const float* __restrict__ g1,
                                                     const float* __restrict__ be1,
                                                     const float* __restrict__ fw,
                                                     double* __restrict__ y2part) {
  __shared__ float h1g[16][64][4];   // [c-granule][point][elem] 16 KB
  const int tid = threadIdx.x;
  const int lane = tid & 63;
  const int wvu = __builtin_amdgcn_readfirstlane(tid >> 6);  // 0..15
  const int o0 = wvu * 8;
  const float* w2t = fw + F_W2T;
  double s64[8], q64[8];
  #pragma unroll
  for (int j = 0; j < 8; ++j) { s64[j] = 0.0; q64[j] = 0.0; }

  float px0, px1, px2;
  {
    int p = blockIdx.x * 64 + lane;
    int b = p >> 14, n = p & (N_ - 1);
    const float* xb = x + (size_t)b * 3 * N_ + n;
    px0 = xb[0]; px1 = xb[N_]; px2 = xb[2 * N_];
  }

  for (int chunk = blockIdx.x; chunk < NCHUNK; chunk += GRID_Y2) {
    __syncthreads();   // prior-iteration readers done before overwrite
    {
      const int c0 = wvu * 4;
      float hv[4];
      #pragma unroll
      for (int k = 0; k < 4; ++k) hv[k] = h1_of(w1, b1, g1, be1, fw, c0 + k, px0, px1, px2);
      float4 v; v.x = hv[0]; v.y = hv[1]; v.z = hv[2]; v.w = hv[3];
      *(float4*)&h1g[wvu][lane][0] = v;
    }
    __syncthreads();
    // prefetch next chunk's x (latency hides under the FMA loop)
    float nx0 = 0.f, nx1 = 0.f, nx2 = 0.f;
    {
      int nchunk = chunk + GRID_Y2;
      if (nchunk < NCHUNK) {
        int p = nchunk * 64 + lane;
        int b = p >> 14, n = p & (N_ - 1);
        const float* xb = x + (size_t)b * 3 * N_ + n;
        nx0 = xb[0]; nx1 = xb[N_]; nx2 = xb[2 * N_];
      }
    }
    float acc[8];
    #pragma unroll
    for (int j = 0; j < 8; ++j) acc[j] = 0.f;
    #pragma unroll 4
    for (int cg = 0; cg < 16; ++cg) {
      float4 hgv = *(const float4*)&h1g[cg][lane][0];
      float hx[4] = {hgv.x, hgv.y, hgv.z, hgv.w};
      #pragma unroll
      for (int e = 0; e < 4; ++e) {
        const int c = cg * 4 + e;
        const float hc = hx[e];
        const float* wc = w2t + c * 128 + o0;
        #pragma unroll
        for (int j = 0; j < 8; ++j) acc[j] = fmaf(wc[j], hc, acc[j]);
      }
    }
    #pragma unroll
    for (int j = 0; j < 8; ++j) {
      double v = (double)acc[j];
      s64[j] += v;
      q64[j] = fma(v, v, q64[j]);
    }
    px0 = nx0; px1 = nx1; px2 = nx2;
  }
  #pragma unroll
  for (int j = 0; j < 8; ++j) {
    #pragma unroll
    for (int m = 32; m >= 1; m >>= 1) {
      s64[j] += __shfl_xor(s64[j], m);
      q64[j] += __shfl_xor(q64[j], m);
    }
  }
  if (lane == 0) {
    #pragma unroll
    for (int j = 0; j < 8; ++j) {
      int o = o0 + j;
      y2part[((size_t)blockIdx.x * 128 + o) * 2 + 0] = s64[j];
      y2part[((size_t)blockIdx.x * 128 + o) * 2 + 1] = q64[j];
    }
  }
}

// ---- K3b: fixed-order partial reduction (1024 partials) + BN2 coeffs, fused ----
__global__ __launch_bounds__(256) void k_redY2p(const double* __restrict__ y2part,
                                                const float* __restrict__ b2,
                                                float* __restrict__ fw) {
  __shared__ double ss[256], sq[256];
  const int o = blockIdx.x, tid = threadIdx.x;
  double s = 0.0, q = 0.0;
  for (int blk = tid; blk < GRID_Y2; blk += 256) {
    s += y2part[((size_t)blk * 128 + o) * 2 + 0];
    q += y2part[((size_t)blk * 128 + o) * 2 + 1];
  }
  ss[tid] = s; sq[tid] = q;
  __syncthreads();
  for (int st = 128; st > 0; st >>= 1) {
    if (tid < st) { ss[tid] += ss[tid + st]; sq[tid] += sq[tid + st]; }
    __syncthreads();
  }
  if (tid == 0) {
    const double inv = 1.0 / (double)NPTS;
    double mraw = ss[0] * inv;
    double var = sq[0] * inv - mraw * mraw;
    fw[F_M2 + o] = (float)(mraw + (double)b2[o]);
    float vpe = (float)var + 1e-5f;
    fw[F_R2 + o] = (float)(1.0 / sqrt((double)vpe));
  }
}

// -------- K5: forward (R16 two-launch version, measured 113 us/half) --------
__global__ __launch_bounds__(512, 4) void k_fwd(const float* __restrict__ x,
                                                const float* __restrict__ w1,
                                                const float* __restrict__ b1,
                                                const float* __restrict__ g1,
                                                const float* __restrict__ be1,
                                                const float* __restrict__ b2,
                                                const float* __restrict__ g2,
                                                const float* __restrict__ be2,
                                                const float* __restrict__ b3,
                                                const float* __restrict__ fw,
                                                float* __restrict__ y3out,
                                                int pbase) {
  __shared__ float h1g[16][64][4];   // 16 KB
  __shared__ float h2g[16][64][4];   // 16 KB
  const int tid = threadIdx.x;
  const int lane = tid & 63;
  const int wvu = __builtin_amdgcn_readfirstlane(tid >> 6);  // 0..7
  const int p = pbase + blockIdx.x * 64 + lane;
  const int b = p >> 14, n = p & (N_ - 1);
  const float* xb = x + (size_t)b * 3 * N_ + n;
  const float x0 = xb[0], x1 = xb[N_], x2 = xb[2 * N_];
  const float* w2t = fw + F_W2T;
  const float* w3t = fw + F_W3T;
  const int q0 = wvu * 8;
  float a3[8];

  {
    const int c0 = wvu * 8;
    float hv[8];
    #pragma unroll
    for (int k = 0; k < 8; ++k) hv[k] = h1_of(w1, b1, g1, be1, fw, c0 + k, x0, x1, x2);
    #pragma unroll
    for (int gq = 0; gq < 2; ++gq) {
      float4 v; v.x = hv[gq*4+0]; v.y = hv[gq*4+1]; v.z = hv[gq*4+2]; v.w = hv[gq*4+3];
      *(float4*)&h1g[(c0 >> 2) + gq][lane][0] = v;
    }
  }
  __syncthreads();

  #pragma unroll
  for (int H = 0; H < 2; ++H) {
    {
      const int o0 = H * 64 + wvu * 8;
      float acc[8];
      #pragma unroll
      for (int j = 0; j < 8; ++j) acc[j] = 0.f;
      #pragma unroll 4
      for (int cg = 0; cg < 16; ++cg) {
        float4 hgv = *(const float4*)&h1g[cg][lane][0];
        float hx[4] = {hgv.x, hgv.y, hgv.z, hgv.w};
        #pragma unroll
        for (int e = 0; e < 4; ++e) {
          const int c = cg * 4 + e;
          const float hc = hx[e];
          const float* wc = w2t + c * 128 + o0;
          #pragma unroll
          for (int j = 0; j < 8; ++j) acc[j] = fmaf(wc[j], hc, acc[j]);
        }
      }
      float hv2[8];
      #pragma unroll
      for (int j = 0; j < 8; ++j) {
        int o = o0 + j;
        float y2 = acc[j] + b2[o];
        float t = y2 - fw[F_M2 + o];
        float u = t * fw[F_R2 + o];
        u = u * g2[o];
        u = u + be2[o];
        hv2[j] = fmaxf(u, 0.f);
      }
      #pragma unroll
      for (int gq = 0; gq < 2; ++gq) {
        float4 v; v.x = hv2[gq*4+0]; v.y = hv2[gq*4+1]; v.z = hv2[gq*4+2]; v.w = hv2[gq*4+3];
        *(float4*)&h2g[wvu * 2 + gq][lane][0] = v;
      }
    }
    __syncthreads();
    {
      #pragma unroll 4
      for (int og = 0; og < 16; ++og) {
        float4 hgv = *(const float4*)&h2g[og][lane][0];
        float hx[4] = {hgv.x, hgv.y, hgv.z, hgv.w};
        #pragma unroll
        for (int e = 0; e < 4; ++e) {
          const int o = H * 64 + og * 4 + e;
          const float ho = hx[e];
          const float* wr = w3t + o * 64 + q0;
          if (H == 0 && og == 0 && e == 0) {
            #pragma unroll
            for (int j = 0; j < 8; ++j) a3[j] = wr[j] * ho;
          } else {
            #pragma unroll
            for (int j = 0; j < 8; ++j) a3[j] = fmaf(wr[j], ho, a3[j]);
          }
        }
      }
    }
    __syncthreads();
  }

  float* yrow = y3out + (size_t)b * 64 * N_ + n;
  #pragma unroll
  for (int j = 0; j < 8; ++j) {
    int q = q0 + j;
    yrow[(size_t)q * N_] = a3[j] + b3[q];
  }
}

__global__ void k_prep3(double* __restrict__ wd, float* __restrict__ fw) {
  int o = threadIdx.x;
  if (o >= 64) return;
  const double inv = 1.0 / (double)NPTS;
  double m = wd[D_Y3SUM + o] * inv;
  double var = wd[D_Y3SQ + o] * inv - m * m;
  fw[F_M3 + o] = (float)m;
  float vpe = (float)var + 1e-5f;
  fw[F_R3 + o] = (float)(1.0 / sqrt((double)vpe));
}

// -------- K6: radix-select top-16 of sgn(g3)*y3 per (b,c) row + fused y3 stats --------
__global__ __launch_bounds__(256) void k_topk(const float* __restrict__ y3,
                                              const float* __restrict__ g3,
                                              int* __restrict__ topk,
                                              double* __restrict__ wd) {
  __shared__ unsigned int hist[4][256];
  __shared__ unsigned int cnt[256];
  __shared__ unsigned long long buf[256];
  __shared__ unsigned int nbuf;
  __shared__ int s_tbin1, s_before1, s_tbin2;
  __shared__ double ssum[256], ssq[256];
  const int tid = threadIdx.x;
  const int row = blockIdx.x;
  const int c = row & 63;
  const int wv = tid >> 6;
  const float sgn = (g3[c] >= 0.f) ? 1.f : -1.f;
  const float4* y = (const float4*)(y3 + (size_t)row * N_);

  for (int i = tid; i < 1024; i += 256) ((unsigned int*)hist)[i] = 0;
  if (tid == 0) nbuf = 0;
  __syncthreads();

  // scan 1: stats (verbatim order) + top-byte histogram
  double s = 0.0, q = 0.0;
  #pragma unroll 1
  for (int it = 0; it < 16; ++it) {
    int n4 = it * 256 + tid;
    float4 v = y[n4];
    {
      double a = v.x, bb = v.y, cc2 = v.z, d = v.w;
      s += a + bb + cc2 + d;
      q = fma(a,a,q); q = fma(bb,bb,q); q = fma(cc2,cc2,q); q = fma(d,d,q);
    }
    unsigned int u0 = okey(sgn * v.x), u1 = okey(sgn * v.y);
    unsigned int u2 = okey(sgn * v.z), u3 = okey(sgn * v.w);
    atomicAdd(&hist[wv][u0 >> 24], 1u);
    atomicAdd(&hist[wv][u1 >> 24], 1u);
    atomicAdd(&hist[wv][u2 >> 24], 1u);
    atomicAdd(&hist[wv][u3 >> 24], 1u);
  }
  ssum[tid] = s; ssq[tid] = q;
  __syncthreads();
  for (int st = 128; st > 0; st >>= 1) {
    if (tid < st) { ssum[tid] += ssum[tid + st]; ssq[tid] += ssq[tid + st]; }
    __syncthreads();
  }
  if (tid == 0) {
    atomicAdd(&wd[D_Y3SUM + c], ssum[0]);
    atomicAdd(&wd[D_Y3SQ  + c], ssq[0]);
  }

  unsigned int myc = hist[0][tid] + hist[1][tid] + hist[2][tid] + hist[3][tid];
  cnt[tid] = myc;
  __syncthreads();
  for (int st = 1; st < 256; st <<= 1) {
    unsigned int t = (tid >= st) ? cnt[tid - st] : 0u;
    __syncthreads();
    cnt[tid] += t;
    __syncthreads();
  }
  {
    unsigned int incl = cnt[tid], excl = incl - myc;
    if (excl < 16u && incl >= 16u) { s_tbin1 = tid; s_before1 = (int)excl; }
  }
  __syncthreads();
  const unsigned int tbin1 = (unsigned int)s_tbin1;
  const int before1 = s_before1;

  for (int i = tid; i < 1024; i += 256) ((unsigned int*)hist)[i] = 0;
  __syncthreads();
  #pragma unroll 1
  for (int it = 0; it < 16; ++it) {
    int n4 = it * 256 + tid;
    float4 v = y[n4];
    unsigned int u0 = okey(sgn * v.x), u1 = okey(sgn * v.y);
    unsigned int u2 = okey(sgn * v.z), u3 = okey(sgn * v.w);
    if ((u0 >> 24) == tbin1) atomicAdd(&hist[wv][(u0 >> 16) & 255u], 1u);
    if ((u1 >> 24) == tbin1) atomicAdd(&hist[wv][(u1 >> 16) & 255u], 1u);
    if ((u2 >> 24) == tbin1) atomicAdd(&hist[wv][(u2 >> 16) & 255u], 1u);
    if ((u3 >> 24) == tbin1) atomicAdd(&hist[wv][(u3 >> 16) & 255u], 1u);
  }
  __syncthreads();
  myc = hist[0][tid] + hist[1][tid] + hist[2][tid] + hist[3][tid];
  cnt[tid] = myc;
  __syncthreads();
  for (int st = 1; st < 256; st <<= 1) {
    unsigned int t = (tid >= st) ? cnt[tid - st] : 0u;
    __syncthreads();
    cnt[tid] += t;
    __syncthreads();
  }
  {
    const unsigned int r2 = (unsigned int)(16 - before1);
    unsigned int incl = cnt[tid], excl = incl - myc;
    if (excl < r2 && incl >= r2) s_tbin2 = tid;
  }
  __syncthreads();
  const unsigned int thresh16 = (tbin1 << 8) | (unsigned int)s_tbin2;

  #pragma unroll 1
  for (int it = 0; it < 16; ++it) {
    int n4 = it * 256 + tid;
    float4 v = y[n4];
    int nb = n4 * 4;
    unsigned int uu[4] = { okey(sgn * v.x), okey(sgn * v.y),
                           okey(sgn * v.z), okey(sgn * v.w) };
    #pragma unroll
    for (int j = 0; j < 4; ++j) {
      if ((uu[j] >> 16) <= thresh16) {
        unsigned int slot = atomicAdd(&nbuf, 1u);
        if (slot < 256u)
          buf[slot] = ((unsigned long long)uu[j] << 32) | (unsigned int)(nb + j);
      }
    }
  }
  __syncthreads();

  if (tid < 64) {
    const unsigned int m = nbuf < 256u ? nbuf : 256u;
    const unsigned long long MAXK = ~0ull;
    unsigned long long k0 = (tid +   0u) < m ? buf[tid +   0] : MAXK;
    unsigned long long k1 = (tid +  64u) < m ? buf[tid +  64] : MAXK;
    unsigned long long k2 = (tid + 128u) < m ? buf[tid + 128] : MAXK;
    unsigned long long k3 = (tid + 192u) < m ? buf[tid + 192] : MAXK;
    #pragma unroll 1
    for (int r = 0; r < 16; ++r) {
      unsigned long long a = k0 < k1 ? k0 : k1;
      unsigned long long b = k2 < k3 ? k2 : k3;
      unsigned long long kmin = a < b ? a : b;
      #pragma unroll
      for (int m2 = 32; m2 >= 1; m2 >>= 1) {
        unsigned long long o = __shfl_xor(kmin, m2);
        kmin = o < kmin ? o : kmin;
      }
      bool have = (k0 == kmin) | (k1 == kmin) | (k2 == kmin) | (k3 == kmin);
      unsigned long long bal = __ballot(have);
      int wlane = __ffsll((unsigned long long)bal) - 1;
      if (tid == wlane) {
        if (k0 == kmin) k0 = MAXK;
        else if (k1 == kmin) k1 = MAXK;
        else if (k2 == kmin) k2 = MAXK;
        else k3 = MAXK;
      }
      if (tid == 0) topk[row * 16 + r] = (int)(kmin & 0xFFFFFFFFull);
    }
  }
}

// ---------------- K7: gather feat (faithful BN3 apply) + idx as float ----------------
__global__ __launch_bounds__(256) void k_gather(const float* __restrict__ x,
                                                const float* __restrict__ fw,
                                                const float* __restrict__ g3,
                                                const float* __restrict__ be3,
                                                const float* __restrict__ y3,
                                                const int* __restrict__ topk,
                                                float* __restrict__ out) {
  __shared__ int s_i[16];
  __shared__ float s_m[64], s_r[64], s_g[64], s_b[64];
  const int tid = threadIdx.x;
  const int row = blockIdx.x;
  const int b = row >> 6, c = row & 63;
  if (tid < 16) s_i[tid] = topk[row * 16 + tid];
  if (tid < 64) {
    s_m[tid] = fw[F_M3 + tid]; s_r[tid] = fw[F_R3 + tid];
    s_g[tid] = g3[tid];        s_b[tid] = be3[tid];
  }
  __syncthreads();
  for (int t = tid; t < 67 * 16; t += 256) {
    int ch = t >> 4, n = t & 15, i = s_i[n];
    float v;
    if (ch < 3) {
      v = x[((size_t)b * 3 + ch) * N_ + i];
    } else {
      int c2 = ch - 3;
      float yv = y3[((size_t)b * 64 + c2) * N_ + i];
      float tt = yv - s_m[c2];
      float u = tt * s_r[c2];
      u = u * s_g[c2];
      v = u + s_b[c2];
    }
    out[(((size_t)b * 67 + ch) * 64 + c) * 16 + n] = v;
  }
  if (tid < 48) {
    int ch = tid >> 4, n = tid & 15;
    out[FEATSZ + (((size_t)b * 3 + ch) * 64 + c) * 16 + n] = (float)s_i[n];
  }
}

extern "C" void kernel_launch(void* const* d_in, const int* in_sizes, int n_in,
                              void* d_out, int out_size, void* d_ws, size_t ws_size,
                              hipStream_t stream) {
  const float* x   = (const float*)d_in[0];
  const float* w1  = (const float*)d_in[1];
  const float* b1  = (const float*)d_in[2];
  const float* g1  = (const float*)d_in[3];
  const float* be1 = (const float*)d_in[4];
  const float* w2  = (const float*)d_in[5];
  const float* b2  = (const float*)d_in[6];
  const float* g2  = (const float*)d_in[7];
  const float* be2 = (const float*)d_in[8];
  const float* w3  = (const float*)d_in[9];
  const float* b3  = (const float*)d_in[10];
  const float* g3  = (const float*)d_in[11];
  const float* be3 = (const float*)d_in[12];
  double* wd = (double*)d_ws;
  float*  fw = (float*)d_ws;
  float*  out = (float*)d_out;
  int* topk = (int*)(fw + F_TOPK);
  double* y2part = (double*)((char*)d_ws + Y2PART_B);
  float*  y3     = (float*)((char*)d_ws + Y3_B);

  hipMemsetAsync(d_ws, 0, 1152, stream);   // zero D_X9..D_Y3SQ (Y3 stats atomics)
  k_xstats64<<<GRID_XS, 256, 0, stream>>>(x, wd);
  k_redX    <<<1, 64, 0, stream>>>(wd);
  k_prep1   <<<1, 64, 0, stream>>>(w1, b1, wd, fw);
  k_prepW   <<<128, 64, 0, stream>>>(w2, w3, fw);
  k_y2stats <<<GRID_Y2, 1024, 0, stream>>>(x, w1, b1, g1, be1, fw, y2part);
  k_redY2p  <<<128, 256, 0, stream>>>(y2part, b2, fw);
  k_fwd     <<<NPTS / 128, 512, 0, stream>>>(x, w1, b1, g1, be1, b2, g2, be2, b3, fw, y3, 0);
  k_fwd     <<<NPTS / 128, 512, 0, stream>>>(x, w1, b1, g1, be1, b2, g2, be2, b3, fw, y3, NPTS / 2);
  k_topk    <<<B_ * 64, 256, 0, stream>>>(y3, g3, topk, wd);
  k_prep3   <<<1, 64, 0, stream>>>(wd, fw);
  k_gather  <<<B_ * 64, 256, 0, stream>>>(x, fw, g3, be3, y3, topk, out);
  (void)in_sizes; (void)n_in; (void)out_size; (void)ws_size;
}